// Round 1
// baseline (858.133 us; speedup 1.0000x reference)
//
#include <hip/hip_runtime.h>
#include <hip/hip_bf16.h>

// QuantizedLinear: out[M,N] = inp[M,K] @ (qw[N,K] * scale[N])^T
// M = 2*2048 = 4096, K = 4096, N = 12288.
// Strategy: bf16 MFMA (16x16x32), fp32 accumulate, scale in epilogue.

#define K_DIM 4096
#define N_DIM 12288

constexpr int BM = 128;
constexpr int BN = 128;
constexpr int BK = 64;
constexpr int PAD = 8;            // bf16 elements of padding per row
constexpr int LDA = BK + PAD;     // 72 ushorts = 144 B row stride
constexpr int LDB = BK + PAD;

typedef float  f32x4  __attribute__((ext_vector_type(4)));
typedef int    i32x4  __attribute__((ext_vector_type(4)));
typedef short  bf16x8 __attribute__((ext_vector_type(8)));   // 8 bf16 in 4 VGPRs
typedef unsigned short u16x4 __attribute__((ext_vector_type(4)));
typedef float  f32x4a __attribute__((ext_vector_type(4)));

__device__ __forceinline__ unsigned short f32_to_bf16(float f) {
    unsigned int u = __builtin_bit_cast(unsigned int, f);
    // round-to-nearest-even
    u += 0x7FFFu + ((u >> 16) & 1u);
    return (unsigned short)(u >> 16);
}

__global__ __launch_bounds__(256)
void qlinear_kernel(const float* __restrict__ A,      // [M, K] fp32
                    const int*   __restrict__ Wq,     // [N, K] int32 (int8 values)
                    const float* __restrict__ Sw,     // [N]
                    float*       __restrict__ Out,    // [M, N]
                    int M) {
    __shared__ unsigned short As[BM][LDA];
    __shared__ unsigned short Bs[BN][LDB];

    const int tid  = threadIdx.x;
    const int lane = tid & 63;
    const int wid  = tid >> 6;          // 0..3
    const int wm   = wid >> 1;          // 0..1 : wave row
    const int wn   = wid & 1;           // 0..1 : wave col

    const int bm = blockIdx.y * BM;
    const int bn = blockIdx.x * BN;

    // staging decomposition: 16 threads per 64-elem k-row (float4/int4 each)
    const int rowT = tid >> 4;          // 0..15
    const int kq   = tid & 15;          // float4 index

    f32x4 acc[4][4];
    #pragma unroll
    for (int i = 0; i < 4; ++i)
        #pragma unroll
        for (int j = 0; j < 4; ++j)
            acc[i][j] = (f32x4){0.f, 0.f, 0.f, 0.f};

    const int c0 = lane & 15;           // fragment col (A row / B row index)
    const int kg = (lane >> 4) * 8;     // fragment k sub-offset

    for (int k0 = 0; k0 < K_DIM; k0 += BK) {
        // ---- stage A: 128 rows x 64 k of fp32 -> bf16 LDS ----
        #pragma unroll
        for (int it = 0; it < 8; ++it) {
            const int r = it * 16 + rowT;
            const f32x4 a4 = *(const f32x4*)(A + (size_t)(bm + r) * K_DIM + k0 + kq * 4);
            u16x4 h;
            h[0] = f32_to_bf16(a4[0]);
            h[1] = f32_to_bf16(a4[1]);
            h[2] = f32_to_bf16(a4[2]);
            h[3] = f32_to_bf16(a4[3]);
            *(u16x4*)&As[r][kq * 4] = h;
        }
        // ---- stage B: 128 rows (n) x 64 k of int32 -> bf16 LDS ----
        #pragma unroll
        for (int it = 0; it < 8; ++it) {
            const int r = it * 16 + rowT;
            const i32x4 w4 = *(const i32x4*)(Wq + (size_t)(bn + r) * K_DIM + k0 + kq * 4);
            u16x4 h;
            h[0] = f32_to_bf16((float)w4[0]);
            h[1] = f32_to_bf16((float)w4[1]);
            h[2] = f32_to_bf16((float)w4[2]);
            h[3] = f32_to_bf16((float)w4[3]);
            *(u16x4*)&Bs[r][kq * 4] = h;
        }
        __syncthreads();

        // ---- compute: 2 k-subtiles of 32 ----
        #pragma unroll
        for (int ks = 0; ks < 2; ++ks) {
            const int kk = ks * 32 + kg;
            bf16x8 af[4], bfr[4];
            #pragma unroll
            for (int mf = 0; mf < 4; ++mf)
                af[mf] = *(const bf16x8*)&As[wm * 64 + mf * 16 + c0][kk];
            #pragma unroll
            for (int nf = 0; nf < 4; ++nf)
                bfr[nf] = *(const bf16x8*)&Bs[wn * 64 + nf * 16 + c0][kk];
            #pragma unroll
            for (int mf = 0; mf < 4; ++mf)
                #pragma unroll
                for (int nf = 0; nf < 4; ++nf)
                    acc[mf][nf] = __builtin_amdgcn_mfma_f32_16x16x32_bf16(
                        af[mf], bfr[nf], acc[mf][nf], 0, 0, 0);
        }
        __syncthreads();
    }

    // ---- epilogue: C/D layout col = lane&15, row = (lane>>4)*4 + j ----
    const int r0 = (lane >> 4) * 4;
    #pragma unroll
    for (int nf = 0; nf < 4; ++nf) {
        const int col = bn + wn * 64 + nf * 16 + c0;
        const float s = Sw[col];
        #pragma unroll
        for (int mf = 0; mf < 4; ++mf) {
            const int rowb = bm + wm * 64 + mf * 16 + r0;
            #pragma unroll
            for (int j = 0; j < 4; ++j)
                Out[(size_t)(rowb + j) * N_DIM + col] = acc[mf][nf][j] * s;
        }
    }
}

extern "C" void kernel_launch(void* const* d_in, const int* in_sizes, int n_in,
                              void* d_out, int out_size, void* d_ws, size_t ws_size,
                              hipStream_t stream) {
    const float* inp = (const float*)d_in[0];
    const int*   qw  = (const int*)d_in[1];
    const float* sw  = (const float*)d_in[2];
    float*       out = (float*)d_out;

    const int M = in_sizes[0] / K_DIM;          // 4096
    dim3 grid(N_DIM / BN, M / BM);              // (96, 32)
    qlinear_kernel<<<grid, 256, 0, stream>>>(inp, qw, sw, out, M);
}

// Round 2
// 763.453 us; speedup vs baseline: 1.1240x; 1.1240x over previous
//
#include <hip/hip_runtime.h>
#include <hip/hip_bf16.h>

// QuantizedLinear: out[M,N] = inp[M,K] @ (qw[N,K] * scale[N])^T
// M = 4096, K = 4096, N = 12288.
// Two-pass: (1) convert A fp32->bf16, W int32->bf16 into d_ws;
//           (2) bf16 MFMA GEMM (m97 structure: global_load_lds w=16, 128^2 tile).

#define K_DIM 4096
#define N_DIM 12288

constexpr int BM = 128;
constexpr int BN = 128;
constexpr int BK = 64;

typedef float  f32x4  __attribute__((ext_vector_type(4)));
typedef int    i32x4  __attribute__((ext_vector_type(4)));
typedef short  bf16x8 __attribute__((ext_vector_type(8)));
typedef unsigned short u16x4 __attribute__((ext_vector_type(4)));
typedef unsigned short u16x8 __attribute__((ext_vector_type(8)));

__device__ __forceinline__ unsigned short f32_to_bf16(float f) {
    unsigned int u = __builtin_bit_cast(unsigned int, f);
    u += 0x7FFFu + ((u >> 16) & 1u);   // round-to-nearest-even
    return (unsigned short)(u >> 16);
}

// ---------------- Pass 1: conversion kernels ----------------

__global__ __launch_bounds__(256)
void cvt_a_kernel(const float* __restrict__ A, unsigned short* __restrict__ Ab, int n8) {
    // each iter: 8 floats -> 8 bf16 (16B store)
    int stride = gridDim.x * blockDim.x;
    for (int i = blockIdx.x * blockDim.x + threadIdx.x; i < n8; i += stride) {
        const f32x4 a0 = *(const f32x4*)(A + (size_t)i * 8);
        const f32x4 a1 = *(const f32x4*)(A + (size_t)i * 8 + 4);
        u16x8 h;
        h[0] = f32_to_bf16(a0[0]); h[1] = f32_to_bf16(a0[1]);
        h[2] = f32_to_bf16(a0[2]); h[3] = f32_to_bf16(a0[3]);
        h[4] = f32_to_bf16(a1[0]); h[5] = f32_to_bf16(a1[1]);
        h[6] = f32_to_bf16(a1[2]); h[7] = f32_to_bf16(a1[3]);
        *(u16x8*)(Ab + (size_t)i * 8) = h;
    }
}

__global__ __launch_bounds__(256)
void cvt_w_kernel(const int* __restrict__ W, unsigned short* __restrict__ Wb, int n8) {
    int stride = gridDim.x * blockDim.x;
    for (int i = blockIdx.x * blockDim.x + threadIdx.x; i < n8; i += stride) {
        const i32x4 w0 = *(const i32x4*)(W + (size_t)i * 8);
        const i32x4 w1 = *(const i32x4*)(W + (size_t)i * 8 + 4);
        u16x8 h;  // int8 values are exact in bf16
        h[0] = f32_to_bf16((float)w0[0]); h[1] = f32_to_bf16((float)w0[1]);
        h[2] = f32_to_bf16((float)w0[2]); h[3] = f32_to_bf16((float)w0[3]);
        h[4] = f32_to_bf16((float)w1[0]); h[5] = f32_to_bf16((float)w1[1]);
        h[6] = f32_to_bf16((float)w1[2]); h[7] = f32_to_bf16((float)w1[3]);
        *(u16x8*)(Wb + (size_t)i * 8) = h;
    }
}

// ---------------- Pass 2: bf16 GEMM (m97 structure) ----------------

__device__ __forceinline__ void gload_lds16(const void* g, void* l) {
    __builtin_amdgcn_global_load_lds(
        (const __attribute__((address_space(1))) unsigned int*)g,
        (__attribute__((address_space(3))) unsigned int*)l,
        16, 0, 0);
}

__global__ __launch_bounds__(256)
void gemm_bf16_kernel(const unsigned short* __restrict__ Ab,  // [M,K] bf16
                      const unsigned short* __restrict__ Wb,  // [N,K] bf16
                      const float* __restrict__ Sw,           // [N]
                      float* __restrict__ Out,                // [M,N]
                      int M) {
    __shared__ unsigned short As[BM * BK];   // 16 KB, linear (global_load_lds dest)
    __shared__ unsigned short Bs[BN * BK];   // 16 KB

    const int tid  = threadIdx.x;
    const int lane = tid & 63;
    const int wid  = tid >> 6;          // 0..3
    const int wm   = wid >> 1;
    const int wn   = wid & 1;

    // XCD-aware swizzle: 3072 blocks, 8 XCDs, 384 blocks per XCD chunk.
    // Column-major within chunk: 32 consecutive blocks share one W-panel (fits L2).
    const int nwgx = N_DIM / BN;        // 96
    const int nwgy = M / BM;            // 32
    const int nwg  = nwgx * nwgy;       // 3072
    const int cpx  = nwg >> 3;          // 384
    const int bid  = blockIdx.x;
    const int swz  = (bid & 7) * cpx + (bid >> 3);
    const int bx   = swz / nwgy;        // N-tile index (shared by 32 consecutive)
    const int by   = swz % nwgy;        // M-tile index

    const int bm = by * BM;
    const int bn = bx * BN;

    // staging: per wave, 4 issues of 1KB per tile (A and B).
    // linear LDS byte = chunk*1024 + lane*16, chunk = i*4 + wid
    // -> row = i*32 + wid*8 + (lane>>3), col = (lane&7)*8 bf16
    const int srow = wid * 8 + (lane >> 3);
    const int scol = (lane & 7) * 8;

    f32x4 acc[4][4];
    #pragma unroll
    for (int i = 0; i < 4; ++i)
        #pragma unroll
        for (int j = 0; j < 4; ++j)
            acc[i][j] = (f32x4){0.f, 0.f, 0.f, 0.f};

    const int c0 = lane & 15;
    const int kg = (lane >> 4) * 8;

    const unsigned short* Abase = Ab + (size_t)bm * K_DIM + scol;
    const unsigned short* Bbase = Wb + (size_t)bn * K_DIM + scol;

    for (int k0 = 0; k0 < K_DIM; k0 += BK) {
        // ---- stage A and B tiles via global_load_lds (16B/lane) ----
        #pragma unroll
        for (int i = 0; i < 4; ++i) {
            gload_lds16(Abase + (size_t)(i * 32 + srow) * K_DIM + k0,
                        &As[(i * 4 + wid) * 512]);
        }
        #pragma unroll
        for (int i = 0; i < 4; ++i) {
            gload_lds16(Bbase + (size_t)(i * 32 + srow) * K_DIM + k0,
                        &Bs[(i * 4 + wid) * 512]);
        }
        __syncthreads();   // drains vmcnt + lgkmcnt

        // ---- compute: 2 k-subtiles of 32 ----
        #pragma unroll
        for (int ks = 0; ks < 2; ++ks) {
            const int kk = ks * 32 + kg;
            bf16x8 af[4], bfr[4];
            #pragma unroll
            for (int mf = 0; mf < 4; ++mf)
                af[mf] = *(const bf16x8*)&As[(wm * 64 + mf * 16 + c0) * BK + kk];
            #pragma unroll
            for (int nf = 0; nf < 4; ++nf)
                bfr[nf] = *(const bf16x8*)&Bs[(wn * 64 + nf * 16 + c0) * BK + kk];
            #pragma unroll
            for (int mf = 0; mf < 4; ++mf)
                #pragma unroll
                for (int nf = 0; nf < 4; ++nf)
                    acc[mf][nf] = __builtin_amdgcn_mfma_f32_16x16x32_bf16(
                        af[mf], bfr[nf], acc[mf][nf], 0, 0, 0);
        }
        __syncthreads();
    }

    // ---- epilogue: C/D layout col = lane&15, row = (lane>>4)*4 + j ----
    const int r0 = (lane >> 4) * 4;
    #pragma unroll
    for (int nf = 0; nf < 4; ++nf) {
        const int col = bn + wn * 64 + nf * 16 + c0;
        const float s = Sw[col];
        #pragma unroll
        for (int mf = 0; mf < 4; ++mf) {
            const int rowb = bm + wm * 64 + mf * 16 + r0;
            #pragma unroll
            for (int j = 0; j < 4; ++j)
                Out[(size_t)(rowb + j) * N_DIM + col] = acc[mf][nf][j] * s;
        }
    }
}

// ---------------- Fallback (round-1 fused kernel) ----------------

constexpr int PAD = 8;
constexpr int LDA = BK + PAD;
constexpr int LDB = BK + PAD;

__global__ __launch_bounds__(256)
void qlinear_fused_kernel(const float* __restrict__ A, const int* __restrict__ Wq,
                          const float* __restrict__ Sw, float* __restrict__ Out, int M) {
    __shared__ unsigned short As[BM][LDA];
    __shared__ unsigned short Bs[BN][LDB];
    const int tid  = threadIdx.x;
    const int lane = tid & 63;
    const int wid  = tid >> 6;
    const int wm   = wid >> 1;
    const int wn   = wid & 1;
    const int bm = blockIdx.y * BM;
    const int bn = blockIdx.x * BN;
    const int rowT = tid >> 4;
    const int kq   = tid & 15;
    f32x4 acc[4][4];
    #pragma unroll
    for (int i = 0; i < 4; ++i)
        #pragma unroll
        for (int j = 0; j < 4; ++j) acc[i][j] = (f32x4){0.f,0.f,0.f,0.f};
    const int c0 = lane & 15;
    const int kg = (lane >> 4) * 8;
    for (int k0 = 0; k0 < K_DIM; k0 += BK) {
        #pragma unroll
        for (int it = 0; it < 8; ++it) {
            const int r = it * 16 + rowT;
            const f32x4 a4 = *(const f32x4*)(A + (size_t)(bm + r) * K_DIM + k0 + kq * 4);
            u16x4 h;
            h[0]=f32_to_bf16(a4[0]); h[1]=f32_to_bf16(a4[1]);
            h[2]=f32_to_bf16(a4[2]); h[3]=f32_to_bf16(a4[3]);
            *(u16x4*)&As[r][kq*4] = h;
        }
        #pragma unroll
        for (int it = 0; it < 8; ++it) {
            const int r = it * 16 + rowT;
            const i32x4 w4 = *(const i32x4*)(Wq + (size_t)(bn + r) * K_DIM + k0 + kq * 4);
            u16x4 h;
            h[0]=f32_to_bf16((float)w4[0]); h[1]=f32_to_bf16((float)w4[1]);
            h[2]=f32_to_bf16((float)w4[2]); h[3]=f32_to_bf16((float)w4[3]);
            *(u16x4*)&Bs[r][kq*4] = h;
        }
        __syncthreads();
        #pragma unroll
        for (int ks = 0; ks < 2; ++ks) {
            const int kk = ks * 32 + kg;
            bf16x8 af[4], bfr[4];
            #pragma unroll
            for (int mf = 0; mf < 4; ++mf)
                af[mf] = *(const bf16x8*)&As[wm*64 + mf*16 + c0][kk];
            #pragma unroll
            for (int nf = 0; nf < 4; ++nf)
                bfr[nf] = *(const bf16x8*)&Bs[wn*64 + nf*16 + c0][kk];
            #pragma unroll
            for (int mf = 0; mf < 4; ++mf)
                #pragma unroll
                for (int nf = 0; nf < 4; ++nf)
                    acc[mf][nf] = __builtin_amdgcn_mfma_f32_16x16x32_bf16(
                        af[mf], bfr[nf], acc[mf][nf], 0, 0, 0);
        }
        __syncthreads();
    }
    const int r0 = (lane >> 4) * 4;
    #pragma unroll
    for (int nf = 0; nf < 4; ++nf) {
        const int col = bn + wn*64 + nf*16 + c0;
        const float s = Sw[col];
        #pragma unroll
        for (int mf = 0; mf < 4; ++mf) {
            const int rowb = bm + wm*64 + mf*16 + r0;
            #pragma unroll
            for (int j = 0; j < 4; ++j)
                Out[(size_t)(rowb + j) * N_DIM + col] = acc[mf][nf][j] * s;
        }
    }
}

extern "C" void kernel_launch(void* const* d_in, const int* in_sizes, int n_in,
                              void* d_out, int out_size, void* d_ws, size_t ws_size,
                              hipStream_t stream) {
    const float* inp = (const float*)d_in[0];
    const int*   qw  = (const int*)d_in[1];
    const float* sw  = (const float*)d_in[2];
    float*       out = (float*)d_out;

    const int M = in_sizes[0] / K_DIM;                         // 4096
    const size_t nA = (size_t)M * K_DIM;                       // 16.7M
    const size_t nW = (size_t)N_DIM * K_DIM;                   // 50.3M
    const size_t need = (nA + nW) * sizeof(unsigned short);    // 128 MiB

    if (ws_size >= need) {
        unsigned short* Ab = (unsigned short*)d_ws;
        unsigned short* Wb = Ab + nA;
        cvt_a_kernel<<<2048, 256, 0, stream>>>(inp, Ab, (int)(nA / 8));
        cvt_w_kernel<<<2048, 256, 0, stream>>>(qw, Wb, (int)(nW / 8));
        dim3 grid((N_DIM / BN) * (M / BM));                    // 3072
        gemm_bf16_kernel<<<grid, 256, 0, stream>>>(Ab, Wb, sw, out, M);
    } else {
        dim3 grid(N_DIM / BN, M / BM);
        qlinear_fused_kernel<<<grid, 256, 0, stream>>>(inp, qw, sw, out, M);
    }
}

// Round 3
// 706.783 us; speedup vs baseline: 1.2141x; 1.0802x over previous
//
#include <hip/hip_runtime.h>
#include <hip/hip_bf16.h>

// QuantizedLinear: out[M,N] = inp[M,K] @ (qw[N,K] * scale[N])^T
// M = 4096, K = 4096, N = 12288.
// Pass 1: convert A fp32->bf16, W int32->bf16 into d_ws.
// Pass 2: bf16 MFMA GEMM, 128^2 tile, BK=64, double-buffered LDS,
//         min-2-phase prefetch, both-sides XOR swizzle (T2, rule #21),
//         global_load_lds width=16, XCD swizzle, setprio.

#define K_DIM 4096
#define N_DIM 12288

constexpr int BM = 128;
constexpr int BN = 128;
constexpr int BK = 64;

typedef float  f32x4  __attribute__((ext_vector_type(4)));
typedef int    i32x4  __attribute__((ext_vector_type(4)));
typedef short  bf16x8 __attribute__((ext_vector_type(8)));
typedef unsigned short u16x4 __attribute__((ext_vector_type(4)));
typedef unsigned short u16x8 __attribute__((ext_vector_type(8)));

__device__ __forceinline__ unsigned short f32_to_bf16(float f) {
    unsigned int u = __builtin_bit_cast(unsigned int, f);
    u += 0x7FFFu + ((u >> 16) & 1u);   // round-to-nearest-even
    return (unsigned short)(u >> 16);
}

// ---------------- Pass 1: conversion kernels ----------------

__global__ __launch_bounds__(256)
void cvt_a_kernel(const float* __restrict__ A, unsigned short* __restrict__ Ab, int n8) {
    int stride = gridDim.x * blockDim.x;
    for (int i = blockIdx.x * blockDim.x + threadIdx.x; i < n8; i += stride) {
        const f32x4 a0 = *(const f32x4*)(A + (size_t)i * 8);
        const f32x4 a1 = *(const f32x4*)(A + (size_t)i * 8 + 4);
        u16x8 h;
        h[0] = f32_to_bf16(a0[0]); h[1] = f32_to_bf16(a0[1]);
        h[2] = f32_to_bf16(a0[2]); h[3] = f32_to_bf16(a0[3]);
        h[4] = f32_to_bf16(a1[0]); h[5] = f32_to_bf16(a1[1]);
        h[6] = f32_to_bf16(a1[2]); h[7] = f32_to_bf16(a1[3]);
        *(u16x8*)(Ab + (size_t)i * 8) = h;
    }
}

__global__ __launch_bounds__(256)
void cvt_w_kernel(const int* __restrict__ W, unsigned short* __restrict__ Wb, int n8) {
    int stride = gridDim.x * blockDim.x;
    for (int i = blockIdx.x * blockDim.x + threadIdx.x; i < n8; i += stride) {
        const i32x4 w0 = *(const i32x4*)(W + (size_t)i * 8);
        const i32x4 w1 = *(const i32x4*)(W + (size_t)i * 8 + 4);
        u16x8 h;  // int8 values are exact in bf16
        h[0] = f32_to_bf16((float)w0[0]); h[1] = f32_to_bf16((float)w0[1]);
        h[2] = f32_to_bf16((float)w0[2]); h[3] = f32_to_bf16((float)w0[3]);
        h[4] = f32_to_bf16((float)w1[0]); h[5] = f32_to_bf16((float)w1[1]);
        h[6] = f32_to_bf16((float)w1[2]); h[7] = f32_to_bf16((float)w1[3]);
        *(u16x8*)(Wb + (size_t)i * 8) = h;
    }
}

// ---------------- Pass 2: bf16 GEMM ----------------

__device__ __forceinline__ void gload_lds16(const void* g, void* l) {
    __builtin_amdgcn_global_load_lds(
        (const __attribute__((address_space(1))) unsigned int*)g,
        (__attribute__((address_space(3))) unsigned int*)l,
        16, 0, 0);
}

__global__ __launch_bounds__(256)
void gemm_bf16_kernel(const unsigned short* __restrict__ Ab,  // [M,K] bf16
                      const unsigned short* __restrict__ Wb,  // [N,K] bf16
                      const float* __restrict__ Sw,           // [N]
                      float* __restrict__ Out,                // [M,N]
                      int M) {
    // double-buffered linear LDS (global_load_lds dest), 64 KiB total
    __shared__ __align__(16) unsigned short As[2][BM * BK];
    __shared__ __align__(16) unsigned short Bs[2][BN * BK];

    const int tid  = threadIdx.x;
    const int lane = tid & 63;
    const int wid  = tid >> 6;          // 0..3
    const int wm   = wid >> 1;
    const int wn   = wid & 1;

    // XCD-aware swizzle: nwg blocks, 8 XCDs, column-major within chunk so
    // 32 consecutive blocks share one W-panel (1 MB, fits per-XCD L2).
    const int nwgy = M / BM;            // 32
    const int nwg  = (N_DIM / BN) * nwgy;
    const int cpx  = nwg >> 3;
    const int bid  = blockIdx.x;
    const int swz  = (bid & 7) * cpx + (bid >> 3);
    const int bx   = swz / nwgy;
    const int by   = swz % nwgy;

    const int bm = by * BM;
    const int bn = bx * BN;

    // --- staging geometry (T2 both-sides swizzle, rule #21) ---
    // LDS linear: chunk c = i*4+wid, lane writes c*1024 + lane*16 bytes
    //   -> (row = c*8 + (lane>>3), colb = (lane&7)*16)
    // want LDS[row][colb] = global[row][colb ^ ((row&7)<<4)]
    //   -> per-lane global col element = ((lane&7) ^ (lane>>3)) * 8
    const int srow = wid * 8 + (lane >> 3);
    const int scol = ((lane & 7) ^ (lane >> 3)) * 8;

    const unsigned short* Abase = Ab + (size_t)bm * K_DIM + scol;
    const unsigned short* Bbase = Wb + (size_t)bn * K_DIM + scol;

    f32x4 acc[4][4];
    #pragma unroll
    for (int i = 0; i < 4; ++i)
        #pragma unroll
        for (int j = 0; j < 4; ++j)
            acc[i][j] = (f32x4){0.f, 0.f, 0.f, 0.f};

    const int c0  = lane & 15;
    const int kg  = (lane >> 4) * 8;
    const int rsw = (c0 & 7) << 3;      // read-side swizzle: row&7 == c0&7

    #define STAGE(buf, k0)                                                     \
        do {                                                                   \
            _Pragma("unroll")                                                  \
            for (int i_ = 0; i_ < 4; ++i_)                                     \
                gload_lds16(Abase + (size_t)(i_ * 32 + srow) * K_DIM + (k0),   \
                            &As[buf][(i_ * 4 + wid) * 512]);                   \
            _Pragma("unroll")                                                  \
            for (int i_ = 0; i_ < 4; ++i_)                                     \
                gload_lds16(Bbase + (size_t)(i_ * 32 + srow) * K_DIM + (k0),   \
                            &Bs[buf][(i_ * 4 + wid) * 512]);                   \
        } while (0)

    constexpr int NT = K_DIM / BK;      // 64

    STAGE(0, 0);
    __syncthreads();                    // drain vmcnt, buf0 ready

    int cur = 0;
    for (int kt = 0; kt < NT; ++kt) {
        if (kt + 1 < NT)
            STAGE(cur ^ 1, (kt + 1) * BK);  // prefetch overlaps compute below

        #pragma unroll
        for (int ks = 0; ks < 2; ++ks) {
            const int kk = (ks * 32 + kg) ^ rsw;   // swizzled read column
            bf16x8 af[4], bfr[4];
            #pragma unroll
            for (int mf = 0; mf < 4; ++mf)
                af[mf] = *(const bf16x8*)&As[cur][(wm * 64 + mf * 16 + c0) * BK + kk];
            #pragma unroll
            for (int nf = 0; nf < 4; ++nf)
                bfr[nf] = *(const bf16x8*)&Bs[cur][(wn * 64 + nf * 16 + c0) * BK + kk];
            __builtin_amdgcn_s_setprio(1);
            #pragma unroll
            for (int mf = 0; mf < 4; ++mf)
                #pragma unroll
                for (int nf = 0; nf < 4; ++nf)
                    acc[mf][nf] = __builtin_amdgcn_mfma_f32_16x16x32_bf16(
                        af[mf], bfr[nf], acc[mf][nf], 0, 0, 0);
            __builtin_amdgcn_s_setprio(0);
        }
        __syncthreads();                // drains prefetch vmcnt + lgkm, one barrier/step
        cur ^= 1;
    }
    #undef STAGE

    // ---- epilogue: C/D layout col = lane&15, row = (lane>>4)*4 + j ----
    const int r0 = (lane >> 4) * 4;
    #pragma unroll
    for (int nf = 0; nf < 4; ++nf) {
        const int col = bn + wn * 64 + nf * 16 + c0;
        const float s = Sw[col];
        #pragma unroll
        for (int mf = 0; mf < 4; ++mf) {
            const int rowb = bm + wm * 64 + mf * 16 + r0;
            #pragma unroll
            for (int j = 0; j < 4; ++j)
                Out[(size_t)(rowb + j) * N_DIM + col] = acc[mf][nf][j] * s;
        }
    }
}

// ---------------- Fallback (round-1 fused kernel) ----------------

constexpr int PAD = 8;
constexpr int LDA = BK + PAD;
constexpr int LDB = BK + PAD;

__global__ __launch_bounds__(256)
void qlinear_fused_kernel(const float* __restrict__ A, const int* __restrict__ Wq,
                          const float* __restrict__ Sw, float* __restrict__ Out, int M) {
    __shared__ unsigned short As[BM][LDA];
    __shared__ unsigned short Bs[BN][LDB];
    const int tid  = threadIdx.x;
    const int lane = tid & 63;
    const int wid  = tid >> 6;
    const int wm   = wid >> 1;
    const int wn   = wid & 1;
    const int bm = blockIdx.y * BM;
    const int bn = blockIdx.x * BN;
    const int rowT = tid >> 4;
    const int kq   = tid & 15;
    f32x4 acc[4][4];
    #pragma unroll
    for (int i = 0; i < 4; ++i)
        #pragma unroll
        for (int j = 0; j < 4; ++j) acc[i][j] = (f32x4){0.f,0.f,0.f,0.f};
    const int c0 = lane & 15;
    const int kg = (lane >> 4) * 8;
    for (int k0 = 0; k0 < K_DIM; k0 += BK) {
        #pragma unroll
        for (int it = 0; it < 8; ++it) {
            const int r = it * 16 + rowT;
            const f32x4 a4 = *(const f32x4*)(A + (size_t)(bm + r) * K_DIM + k0 + kq * 4);
            u16x4 h;
            h[0]=f32_to_bf16(a4[0]); h[1]=f32_to_bf16(a4[1]);
            h[2]=f32_to_bf16(a4[2]); h[3]=f32_to_bf16(a4[3]);
            *(u16x4*)&As[r][kq*4] = h;
        }
        #pragma unroll
        for (int it = 0; it < 8; ++it) {
            const int r = it * 16 + rowT;
            const i32x4 w4 = *(const i32x4*)(Wq + (size_t)(bn + r) * K_DIM + k0 + kq * 4);
            u16x4 h;
            h[0]=f32_to_bf16((float)w4[0]); h[1]=f32_to_bf16((float)w4[1]);
            h[2]=f32_to_bf16((float)w4[2]); h[3]=f32_to_bf16((float)w4[3]);
            *(u16x4*)&Bs[r][kq*4] = h;
        }
        __syncthreads();
        #pragma unroll
        for (int ks = 0; ks < 2; ++ks) {
            const int kk = ks * 32 + kg;
            bf16x8 af[4], bfr[4];
            #pragma unroll
            for (int mf = 0; mf < 4; ++mf)
                af[mf] = *(const bf16x8*)&As[wm*64 + mf*16 + c0][kk];
            #pragma unroll
            for (int nf = 0; nf < 4; ++nf)
                bfr[nf] = *(const bf16x8*)&Bs[wn*64 + nf*16 + c0][kk];
            #pragma unroll
            for (int mf = 0; mf < 4; ++mf)
                #pragma unroll
                for (int nf = 0; nf < 4; ++nf)
                    acc[mf][nf] = __builtin_amdgcn_mfma_f32_16x16x32_bf16(
                        af[mf], bfr[nf], acc[mf][nf], 0, 0, 0);
        }
        __syncthreads();
    }
    const int r0 = (lane >> 4) * 4;
    #pragma unroll
    for (int nf = 0; nf < 4; ++nf) {
        const int col = bn + wn*64 + nf*16 + c0;
        const float s = Sw[col];
        #pragma unroll
        for (int mf = 0; mf < 4; ++mf) {
            const int rowb = bm + wm*64 + mf*16 + r0;
            #pragma unroll
            for (int j = 0; j < 4; ++j)
                Out[(size_t)(rowb + j) * N_DIM + col] = acc[mf][nf][j] * s;
        }
    }
}

extern "C" void kernel_launch(void* const* d_in, const int* in_sizes, int n_in,
                              void* d_out, int out_size, void* d_ws, size_t ws_size,
                              hipStream_t stream) {
    const float* inp = (const float*)d_in[0];
    const int*   qw  = (const int*)d_in[1];
    const float* sw  = (const float*)d_in[2];
    float*       out = (float*)d_out;

    const int M = in_sizes[0] / K_DIM;                         // 4096
    const size_t nA = (size_t)M * K_DIM;
    const size_t nW = (size_t)N_DIM * K_DIM;
    const size_t need = (nA + nW) * sizeof(unsigned short);    // 128 MiB

    if (ws_size >= need) {
        unsigned short* Ab = (unsigned short*)d_ws;
        unsigned short* Wb = Ab + nA;
        cvt_a_kernel<<<2048, 256, 0, stream>>>(inp, Ab, (int)(nA / 8));
        cvt_w_kernel<<<2048, 256, 0, stream>>>(qw, Wb, (int)(nW / 8));
        dim3 grid((N_DIM / BN) * (M / BM));                    // 3072
        gemm_bf16_kernel<<<grid, 256, 0, stream>>>(Ab, Wb, sw, out, M);
    } else {
        dim3 grid(N_DIM / BN, M / BM);
        qlinear_fused_kernel<<<grid, 256, 0, stream>>>(inp, qw, sw, out, M);
    }
}

// Round 4
// 551.010 us; speedup vs baseline: 1.5574x; 1.2827x over previous
//
#include <hip/hip_runtime.h>
#include <hip/hip_bf16.h>

// QuantizedLinear: out[M,N] = inp[M,K] @ (qw[N,K] * scale[N])^T
// M = 4096, K = 4096, N = 12288.
// Pass 1: convert A fp32->bf16, W int32->bf16 into d_ws.
// Pass 2: 256x256 8-phase bf16 GEMM (T1 XCD swizzle, T2 both-sides XOR swizzle,
//         T3+T4 8-phase counted vmcnt, T5 setprio), global_load_lds w=16.

#define K_DIM 4096
#define N_DIM 12288

constexpr int BM = 256;
constexpr int BN = 256;
constexpr int BK = 64;
constexpr int NT = K_DIM / BK;   // 64

typedef float  f32x4  __attribute__((ext_vector_type(4)));
typedef int    i32x4  __attribute__((ext_vector_type(4)));
typedef short  bf16x8 __attribute__((ext_vector_type(8)));
typedef unsigned short u16x8 __attribute__((ext_vector_type(8)));
typedef unsigned short u16x4 __attribute__((ext_vector_type(4)));

__device__ __forceinline__ unsigned short f32_to_bf16(float f) {
    unsigned int u = __builtin_bit_cast(unsigned int, f);
    u += 0x7FFFu + ((u >> 16) & 1u);   // round-to-nearest-even
    return (unsigned short)(u >> 16);
}

// ---------------- Pass 1: conversion kernels ----------------

__global__ __launch_bounds__(256)
void cvt_a_kernel(const float* __restrict__ A, unsigned short* __restrict__ Ab, int n8) {
    int stride = gridDim.x * blockDim.x;
    for (int i = blockIdx.x * blockDim.x + threadIdx.x; i < n8; i += stride) {
        const f32x4 a0 = *(const f32x4*)(A + (size_t)i * 8);
        const f32x4 a1 = *(const f32x4*)(A + (size_t)i * 8 + 4);
        u16x8 h;
        h[0] = f32_to_bf16(a0[0]); h[1] = f32_to_bf16(a0[1]);
        h[2] = f32_to_bf16(a0[2]); h[3] = f32_to_bf16(a0[3]);
        h[4] = f32_to_bf16(a1[0]); h[5] = f32_to_bf16(a1[1]);
        h[6] = f32_to_bf16(a1[2]); h[7] = f32_to_bf16(a1[3]);
        *(u16x8*)(Ab + (size_t)i * 8) = h;
    }
}

__global__ __launch_bounds__(256)
void cvt_w_kernel(const int* __restrict__ W, unsigned short* __restrict__ Wb, int n8) {
    int stride = gridDim.x * blockDim.x;
    for (int i = blockIdx.x * blockDim.x + threadIdx.x; i < n8; i += stride) {
        const i32x4 w0 = *(const i32x4*)(W + (size_t)i * 8);
        const i32x4 w1 = *(const i32x4*)(W + (size_t)i * 8 + 4);
        u16x8 h;  // int8 values are exact in bf16
        h[0] = f32_to_bf16((float)w0[0]); h[1] = f32_to_bf16((float)w0[1]);
        h[2] = f32_to_bf16((float)w0[2]); h[3] = f32_to_bf16((float)w0[3]);
        h[4] = f32_to_bf16((float)w1[0]); h[5] = f32_to_bf16((float)w1[1]);
        h[6] = f32_to_bf16((float)w1[2]); h[7] = f32_to_bf16((float)w1[3]);
        *(u16x8*)(Wb + (size_t)i * 8) = h;
    }
}

// ---------------- Pass 2: 256^2 8-phase bf16 GEMM ----------------

__device__ __forceinline__ void gload_lds16(const void* g, void* l) {
    __builtin_amdgcn_global_load_lds(
        (const __attribute__((address_space(1))) unsigned int*)g,
        (__attribute__((address_space(3))) unsigned int*)l,
        16, 0, 0);
}

__global__ __launch_bounds__(512, 2)
void gemm_bf16_256(const unsigned short* __restrict__ Ab,  // [M,K] bf16
                   const unsigned short* __restrict__ Wb,  // [N,K] bf16
                   const float* __restrict__ Sw,           // [N]
                   float* __restrict__ Out,                // [M,N]
                   int M) {
    // 2 K-tile buffers: A 2x32KB + B 2x32KB = 128 KiB
    __shared__ __align__(16) unsigned short As[2][BM * BK];
    __shared__ __align__(16) unsigned short Bs[2][BN * BK];

    const int tid  = threadIdx.x;
    const int lane = tid & 63;
    const int wid  = tid >> 6;          // 0..7
    const int wm   = wid >> 2;          // 0..1  (128-row half)
    const int wn   = wid & 3;           // 0..3  (64-col strip)

    // T1: XCD swizzle, column-major within chunk (16 blocks share W panel, 2MB -> L2)
    const int nwgy = M / BM;            // 16
    const int nwg  = (N_DIM / BN) * nwgy;   // 768 (%8 == 0)
    const int cpx  = nwg >> 3;          // 96
    const int bid  = blockIdx.x;
    const int swz  = (bid & 7) * cpx + (bid >> 3);
    const int bx   = swz / nwgy;
    const int by   = swz % nwgy;
    const int bm   = by * BM;
    const int bn   = bx * BN;

    // staging: half-tile = 128 rows x 64 k = 16 KB; 512 thr x 16 B x 2 issues.
    // chunk c = j*8+wid -> LDS c*1024B + lane*16B -> row c*8+(lane>>3), colb (lane&7)*16.
    // T2 (rule #21): pre-swizzle GLOBAL col by row&7; LDS stays linear.
    const int srow = wid * 8 + (lane >> 3);                 // 0..63
    const int scol = ((lane & 7) ^ (lane >> 3)) * 8;        // swizzled col (elems)

    #define STG(G, grow0, k0, L)                                                   \
        do {                                                                       \
            gload_lds16((G) + (size_t)((grow0) + srow) * K_DIM + (k0) + scol,      \
                        (L) + wid * 512);                                          \
            gload_lds16((G) + (size_t)((grow0) + 64 + srow) * K_DIM + (k0) + scol, \
                        (L) + (8 + wid) * 512);                                    \
        } while (0)

    f32x4 acc[8][4];
    #pragma unroll
    for (int i = 0; i < 8; ++i)
        #pragma unroll
        for (int j = 0; j < 4; ++j)
            acc[i][j] = (f32x4){0.f, 0.f, 0.f, 0.f};

    const int c0  = lane & 15;
    const int kg  = (lane >> 4) * 8;
    const int rsw = (c0 & 7) * 8;       // read-side swizzle (row&7 == c0&7)

    // ---- prologue: tile0 complete + A-halves of tile1; 4 loads stay in flight ----
    STG(Ab, bm,       0, &As[0][0]);        // A0(0)
    STG(Ab, bm + 128, 0, &As[0][8192]);     // A1(0)
    STG(Wb, bn,       0, &Bs[0][0]);        // B0(0)
    STG(Wb, bn + 128, 0, &Bs[0][8192]);     // B1(0)
    STG(Ab, bm,       BK, &As[1][0]);       // A0(1)
    STG(Ab, bm + 128, BK, &As[1][8192]);    // A1(1)
    asm volatile("s_waitcnt vmcnt(4)" ::: "memory");   // tile0 landed; A(1) in flight
    __builtin_amdgcn_s_barrier();

    bf16x8 af[8][2];   // all 8 m-frags x 2 k-slices of current tile (in regs)
    bf16x8 bf[2][2];   // current qn's 2 n-frags x 2 k-slices

    #define MFMA_QUAD(qm, qn)                                                        \
        __builtin_amdgcn_s_setprio(1);                                              \
        _Pragma("unroll") for (int mf = 0; mf < 4; ++mf)                            \
        _Pragma("unroll") for (int nf = 0; nf < 2; ++nf)                            \
        _Pragma("unroll") for (int ks = 0; ks < 2; ++ks)                            \
            acc[(qm)*4 + mf][(qn)*2 + nf] = __builtin_amdgcn_mfma_f32_16x16x32_bf16( \
                af[(qm)*4 + mf][ks], bf[nf][ks], acc[(qm)*4 + mf][(qn)*2 + nf],      \
                0, 0, 0);                                                            \
        __builtin_amdgcn_s_setprio(0);

    for (int t = 0; t < NT; ++t) {
        const int cur = t & 1;
        const unsigned short* Ac = &As[cur][(wm * 128 + c0) * 64];
        const unsigned short* Bc = &Bs[cur][(wn * 64 + c0) * 64];
        unsigned short* Anx_cur = &As[cur][0];      // A(t+2) goes into CUR buffer
        unsigned short* Bnx     = &Bs[cur ^ 1][0];  // B(t+1) goes into NEXT buffer
        const int k1 = (t + 1) * BK;
        const int k2 = (t + 2) * BK;

        // ---- phase 0: quadrant (qm=0, qn=0); stage B0(t+1) ----
        #pragma unroll
        for (int mf = 0; mf < 4; ++mf)
            #pragma unroll
            for (int ks = 0; ks < 2; ++ks)
                af[mf][ks] = *(const bf16x8*)&Ac[(mf * 16) * 64 + ((ks * 32 + kg) ^ rsw)];
        #pragma unroll
        for (int nf = 0; nf < 2; ++nf)
            #pragma unroll
            for (int ks = 0; ks < 2; ++ks)
                bf[nf][ks] = *(const bf16x8*)&Bc[(nf * 16) * 64 + ((ks * 32 + kg) ^ rsw)];
        if (t + 1 < NT) STG(Wb, bn, k1, Bnx);
        __builtin_amdgcn_s_barrier();
        asm volatile("s_waitcnt lgkmcnt(0)");
        MFMA_QUAD(0, 0);
        __builtin_amdgcn_s_barrier();

        // ---- phase 1: quadrant (1,0); stage B1(t+1). After this phase all A(cur)
        //      reads are retired (A held in regs) -> cur A slots become writable. ----
        #pragma unroll
        for (int mf = 0; mf < 4; ++mf)
            #pragma unroll
            for (int ks = 0; ks < 2; ++ks)
                af[4 + mf][ks] = *(const bf16x8*)&Ac[((64 + mf * 16)) * 64 + ((ks * 32 + kg) ^ rsw)];
        if (t + 1 < NT) STG(Wb, bn + 128, k1, Bnx + 8192);
        __builtin_amdgcn_s_barrier();
        asm volatile("s_waitcnt lgkmcnt(0)");
        MFMA_QUAD(1, 0);
        __builtin_amdgcn_s_barrier();

        // ---- phase 2: quadrant (0,1); stage A0(t+2) into cur (safe post-ph1 barrier) ----
        #pragma unroll
        for (int nf = 0; nf < 2; ++nf)
            #pragma unroll
            for (int ks = 0; ks < 2; ++ks)
                bf[nf][ks] = *(const bf16x8*)&Bc[(32 + nf * 16) * 64 + ((ks * 32 + kg) ^ rsw)];
        if (t + 2 < NT) STG(Ab, bm, k2, Anx_cur);
        __builtin_amdgcn_s_barrier();
        asm volatile("s_waitcnt lgkmcnt(0)");
        MFMA_QUAD(0, 1);
        __builtin_amdgcn_s_barrier();

        // ---- phase 3: quadrant (1,1); stage A1(t+2); counted vmcnt at tile end ----
        if (t + 2 < NT) STG(Ab, bm + 128, k2, Anx_cur + 8192);
        __builtin_amdgcn_s_barrier();
        MFMA_QUAD(1, 1);
        // queue: [A(t+1) x4 (old), B(t+1) x4, A(t+2) x4] -> keep A(t+2) in flight
        if (t < NT - 2) {
            asm volatile("s_waitcnt vmcnt(4)" ::: "memory");
        } else if (t == NT - 2) {
            asm volatile("s_waitcnt vmcnt(0)" ::: "memory");
        }
        if (t < NT - 1) __builtin_amdgcn_s_barrier();
    }
    #undef MFMA_QUAD
    #undef STG

    // ---- epilogue: C/D col = lane&15 (B row), row = (lane>>4)*4 + j (A row) ----
    const int r0 = (lane >> 4) * 4;
    #pragma unroll
    for (int n = 0; n < 4; ++n) {
        const int col = bn + wn * 64 + n * 16 + c0;
        const float s = Sw[col];
        #pragma unroll
        for (int m = 0; m < 8; ++m) {
            const int rowb = bm + wm * 128 + m * 16 + r0;
            #pragma unroll
            for (int j = 0; j < 4; ++j)
                Out[(size_t)(rowb + j) * N_DIM + col] = acc[m][n][j] * s;
        }
    }
}

// ---------------- Fallback (fused, if ws too small) ----------------

constexpr int FBM = 128, FBN = 128, FBK = 64, FPAD = 8;

__global__ __launch_bounds__(256)
void qlinear_fused_kernel(const float* __restrict__ A, const int* __restrict__ Wq,
                          const float* __restrict__ Sw, float* __restrict__ Out, int M) {
    __shared__ unsigned short Asf[FBM][FBK + FPAD];
    __shared__ unsigned short Bsf[FBN][FBK + FPAD];
    const int tid  = threadIdx.x;
    const int lane = tid & 63;
    const int wid  = tid >> 6;
    const int wm   = wid >> 1;
    const int wn   = wid & 1;
    const int bm = blockIdx.y * FBM;
    const int bn = blockIdx.x * FBN;
    const int rowT = tid >> 4;
    const int kq   = tid & 15;
    f32x4 acc[4][4];
    #pragma unroll
    for (int i = 0; i < 4; ++i)
        #pragma unroll
        for (int j = 0; j < 4; ++j) acc[i][j] = (f32x4){0.f,0.f,0.f,0.f};
    const int c0 = lane & 15;
    const int kg = (lane >> 4) * 8;
    for (int k0 = 0; k0 < K_DIM; k0 += FBK) {
        #pragma unroll
        for (int it = 0; it < 8; ++it) {
            const int r = it * 16 + rowT;
            const f32x4 a4 = *(const f32x4*)(A + (size_t)(bm + r) * K_DIM + k0 + kq * 4);
            u16x4 h;
            h[0]=f32_to_bf16(a4[0]); h[1]=f32_to_bf16(a4[1]);
            h[2]=f32_to_bf16(a4[2]); h[3]=f32_to_bf16(a4[3]);
            *(u16x4*)&Asf[r][kq*4] = h;
        }
        #pragma unroll
        for (int it = 0; it < 8; ++it) {
            const int r = it * 16 + rowT;
            const i32x4 w4 = *(const i32x4*)(Wq + (size_t)(bn + r) * K_DIM + k0 + kq * 4);
            u16x4 h;
            h[0]=f32_to_bf16((float)w4[0]); h[1]=f32_to_bf16((float)w4[1]);
            h[2]=f32_to_bf16((float)w4[2]); h[3]=f32_to_bf16((float)w4[3]);
            *(u16x4*)&Bsf[r][kq*4] = h;
        }
        __syncthreads();
        #pragma unroll
        for (int ks = 0; ks < 2; ++ks) {
            const int kk = ks * 32 + kg;
            bf16x8 af[4], bfr[4];
            #pragma unroll
            for (int mf = 0; mf < 4; ++mf)
                af[mf] = *(const bf16x8*)&Asf[wm*64 + mf*16 + c0][kk];
            #pragma unroll
            for (int nf = 0; nf < 4; ++nf)
                bfr[nf] = *(const bf16x8*)&Bsf[wn*64 + nf*16 + c0][kk];
            #pragma unroll
            for (int mf = 0; mf < 4; ++mf)
                #pragma unroll
                for (int nf = 0; nf < 4; ++nf)
                    acc[mf][nf] = __builtin_amdgcn_mfma_f32_16x16x32_bf16(
                        af[mf], bfr[nf], acc[mf][nf], 0, 0, 0);
        }
        __syncthreads();
    }
    const int r0 = (lane >> 4) * 4;
    #pragma unroll
    for (int nf = 0; nf < 4; ++nf) {
        const int col = bn + wn*64 + nf*16 + c0;
        const float s = Sw[col];
        #pragma unroll
        for (int mf = 0; mf < 4; ++mf) {
            const int rowb = bm + wm*64 + mf*16 + r0;
            #pragma unroll
            for (int j = 0; j < 4; ++j)
                Out[(size_t)(rowb + j) * N_DIM + col] = acc[mf][nf][j] * s;
        }
    }
}

extern "C" void kernel_launch(void* const* d_in, const int* in_sizes, int n_in,
                              void* d_out, int out_size, void* d_ws, size_t ws_size,
                              hipStream_t stream) {
    const float* inp = (const float*)d_in[0];
    const int*   qw  = (const int*)d_in[1];
    const float* sw  = (const float*)d_in[2];
    float*       out = (float*)d_out;

    const int M = in_sizes[0] / K_DIM;                         // 4096
    const size_t nA = (size_t)M * K_DIM;
    const size_t nW = (size_t)N_DIM * K_DIM;
    const size_t need = (nA + nW) * sizeof(unsigned short);    // 128 MiB

    if (ws_size >= need && (M % BM) == 0) {
        unsigned short* Abf = (unsigned short*)d_ws;
        unsigned short* Wbf = Abf + nA;
        cvt_a_kernel<<<2048, 256, 0, stream>>>(inp, Abf, (int)(nA / 8));
        cvt_w_kernel<<<2048, 256, 0, stream>>>(qw, Wbf, (int)(nW / 8));
        dim3 grid((N_DIM / BN) * (M / BM));                    // 768
        gemm_bf16_256<<<grid, 512, 0, stream>>>(Abf, Wbf, sw, out, M);
    } else {
        dim3 grid(N_DIM / FBN, M / FBM);
        qlinear_fused_kernel<<<grid, 256, 0, stream>>>(inp, qw, sw, out, M);
    }
}